// Round 10
// baseline (706.174 us; speedup 1.0000x reference)
//
#include <hip/hip_runtime.h>

#define B_ 256
#define T_ 1024
#define F_ 64
#define H_ 32
#define V_ 13
#define K4 128   // 4*H

typedef _Float16 f16x8 __attribute__((ext_vector_type(8)));
typedef __fp16   fp16x2 __attribute__((ext_vector_type(2)));   // cvt_pkrtz return type
typedef float    f32x4 __attribute__((ext_vector_type(4)));
typedef unsigned int u32x4 __attribute__((ext_vector_type(4)));

__device__ __forceinline__ void fma4(float4& acc, float s, const float4& wv) {
  acc.x = fmaf(s, wv.x, acc.x);
  acc.y = fmaf(s, wv.y, acc.y);
  acc.z = fmaf(s, wv.z, acc.z);
  acc.w = fmaf(s, wv.w, acc.w);
}

// ---------------- Kernel A: xz = x @ W + b  ([B*T,64] @ [64,128]) ----------------
__global__ __launch_bounds__(256, 2) void xz_gemm(const float* __restrict__ x,
                                                  const float* __restrict__ W,
                                                  const float* __restrict__ bias,
                                                  float* __restrict__ xz) {
  __shared__ float4 Ws4[F_ * 32];    // W[f][0..127] as 32 float4 per f   (32 KB)
  __shared__ float4 Xs4[128 * 16];   // x[r][0..63]  as 16 float4 per row (32 KB)

  const float4* W4 = (const float4*)W;
  for (int i = threadIdx.x; i < F_ * 32; i += 256) Ws4[i] = W4[i];
  const int row0 = blockIdx.x * 128;
  const float4* X4 = (const float4*)(x + (size_t)row0 * F_);
  for (int i = threadIdx.x; i < 128 * 16; i += 256) Xs4[i] = X4[i];
  __syncthreads();

  const int cg = threadIdx.x & 31;   // column group: cols 4*cg .. 4*cg+3
  const int rs = threadIdx.x >> 5;   // row slot 0..7; rows rs + 8*rr
  const float4 bv = ((const float4*)bias)[cg];

  float4 acc[16];
#pragma unroll
  for (int rr = 0; rr < 16; ++rr) acc[rr] = bv;

#pragma unroll
  for (int fg = 0; fg < 16; ++fg) {                 // 4 f-values per iteration
    float4 w0 = Ws4[(4 * fg + 0) * 32 + cg];
    float4 w1 = Ws4[(4 * fg + 1) * 32 + cg];
    float4 w2 = Ws4[(4 * fg + 2) * 32 + cg];
    float4 w3 = Ws4[(4 * fg + 3) * 32 + cg];
#pragma unroll
    for (int rr = 0; rr < 16; ++rr) {
      float4 xv = Xs4[(rs + 8 * rr) * 16 + fg];
      fma4(acc[rr], xv.x, w0);
      fma4(acc[rr], xv.y, w1);
      fma4(acc[rr], xv.z, w2);
      fma4(acc[rr], xv.w, w3);
    }
  }
#pragma unroll
  for (int rr = 0; rr < 16; ++rr) {
    ((float4*)(xz + (size_t)(row0 + rs + 8 * rr) * K4))[cg] = acc[rr];
  }
}

// ---------------- Kernel B: LSTM scan — split-precision MFMA recurrence ----------------
// R5 structure (absmax 1.46e-2 proved layout correct, f16 precision insufficient),
// now with h and U split into f16 pairs: v = v_hi + 2^-11 * v_lo_s (lo stored x2048
// to stay in f16 normal range; MFMA may flush denormals).
//   z = h@U = hi.hi + 2^-11*(hi.lo_s + lo_s.hi)   [dropped lo.lo ~ 2^-22]
// Layout per 16x16x32 f16 MFMA (A = h replicated over rows; row-perm cancels since
// A,B share the k-indexing; C/D col = lane&15 HW-verified):
//   chunk c covers permuted z-cols sigma(c,m)=32*(c>>1)+2m+(c&1), m=lane&15
//   -> lane m owns full gate set of units (2m,2m+1): z[0,1]=i z[2,3]=f z[4,5]=g z[6,7]=o
//   h pair packs to one dword; next step's A-frag dword j = bpermute from lane 4g+j.
__device__ __forceinline__ float sigmoid_(float x) { return 1.f / (1.f + __expf(-x)); }
__device__ __forceinline__ float tanh_(float x)    { return 1.f - 2.f / (__expf(2.f * x) + 1.f); }

__global__ __launch_bounds__(256)
__attribute__((amdgpu_waves_per_eu(1, 1)))
void lstm_scan(float* __restrict__ zbuf, const float* __restrict__ U) {
  const int lane = threadIdx.x & 63;
  const int wv   = threadIdx.x >> 6;     // 4 waves/block, one batch per wave
  const int batch = blockIdx.x * 4 + wv;
  const int g = lane >> 4;               // k-block: A/B k = 8g+e
  const int m = lane & 15;               // output column / unit-pair index

  // U fragments, split f16. Loaded once; asm pin keeps them live.
  f16x8 ufh[8], ufl[8];
#pragma unroll
  for (int c = 0; c < 8; ++c) {
    const int col = 32 * (c >> 1) + 2 * m + (c & 1);
#pragma unroll
    for (int e = 0; e < 8; ++e) {
      const float u = U[(8 * g + e) * K4 + col];
      const _Float16 uh = (_Float16)u;
      ufh[c][e] = uh;
      ufl[c][e] = (_Float16)((u - (float)uh) * 2048.0f);
    }
  }
  asm volatile("" : "+v"(ufh[0]), "+v"(ufh[1]), "+v"(ufh[2]), "+v"(ufh[3]),
                    "+v"(ufh[4]), "+v"(ufh[5]), "+v"(ufh[6]), "+v"(ufh[7]));
  asm volatile("" : "+v"(ufl[0]), "+v"(ufl[1]), "+v"(ufl[2]), "+v"(ufl[3]),
                    "+v"(ufl[4]), "+v"(ufl[5]), "+v"(ufl[6]), "+v"(ufl[7]));

  float* zb = zbuf + (size_t)batch * T_ * K4;
  const float* xp = zb + 2 * m;          // xz pair base: cols (2m,2m+1) + 32a

  // 4-deep prefetch: pre[s][a] = xz[t][cols 32a+2m, 32a+2m+1]
  float2 pre[4][4];
#pragma unroll
  for (int s = 0; s < 4; ++s)
#pragma unroll
    for (int a = 0; a < 4; ++a)
      pre[s][a] = *(const float2*)(xp + s * K4 + 32 * a);

  const int bpa = 16 * g;                // bpermute byte addr: 4*(4g+j) = 16g+4j
  int hph = 0, hpl = 0;                  // packed f16 pairs: (h_hi) and (h_lo*2048)
  float c0 = 0.f, c1 = 0.f;
  const f32x4 zz = {0.f, 0.f, 0.f, 0.f};
  const bool st = (lane < 16);

  auto step = [&](float2 (&pr)[4], int t, int tl) {
    // A fragments via 8 bpermutes (all groups read lanes 0..15's packed pairs)
    u32x4 bh, bl;
    bh.x = __builtin_amdgcn_ds_bpermute(bpa + 0,  hph);
    bh.y = __builtin_amdgcn_ds_bpermute(bpa + 4,  hph);
    bh.z = __builtin_amdgcn_ds_bpermute(bpa + 8,  hph);
    bh.w = __builtin_amdgcn_ds_bpermute(bpa + 12, hph);
    bl.x = __builtin_amdgcn_ds_bpermute(bpa + 0,  hpl);
    bl.y = __builtin_amdgcn_ds_bpermute(bpa + 4,  hpl);
    bl.z = __builtin_amdgcn_ds_bpermute(bpa + 8,  hpl);
    bl.w = __builtin_amdgcn_ds_bpermute(bpa + 12, hpl);
    const f16x8 afh = __builtin_bit_cast(f16x8, bh);
    const f16x8 afl = __builtin_bit_cast(f16x8, bl);

    float z[8];
#pragma unroll
    for (int a = 0; a < 4; ++a) {
#pragma unroll
      for (int p = 0; p < 2; ++p) {
        const int cc = 2 * a + p;
        f32x4 mn = __builtin_amdgcn_mfma_f32_16x16x32_f16(afh, ufh[cc], zz, 0, 0, 0);
        f32x4 cr = __builtin_amdgcn_mfma_f32_16x16x32_f16(afh, ufl[cc], zz, 0, 0, 0);
        cr = __builtin_amdgcn_mfma_f32_16x16x32_f16(afl, ufh[cc], cr, 0, 0, 0);
        const float xzv = p ? pr[a].y : pr[a].x;
        z[cc] = fmaf(cr[0], 4.8828125e-4f, mn[0] + xzv);
      }
    }

    // prefetch next (consumed 4 steps later; clamped loads never consumed)
    const int tc = (tl < T_) ? tl : (T_ - 1);
    const float* xq = xp + (size_t)tc * K4;
#pragma unroll
    for (int a = 0; a < 4; ++a) pr[a] = *(const float2*)(xq + 32 * a);

    const float i0 = sigmoid_(z[0]), i1 = sigmoid_(z[1]);
    const float f0 = sigmoid_(z[2]), f1 = sigmoid_(z[3]);
    const float g0 = tanh_(z[4]),    g1 = tanh_(z[5]);
    const float o0 = sigmoid_(z[6]), o1 = sigmoid_(z[7]);
    c0 = fmaf(f0, c0, i0 * g0);
    c1 = fmaf(f1, c1, i1 * g1);
    const float h0 = o0 * tanh_(c0);
    const float h1 = o1 * tanh_(c1);

    if (st) *(float2*)(zb + (size_t)t * K4 + 2 * m) = make_float2(h0, h1);  // fp32 h out

    // split-pack h for next step's fragments
    const fp16x2 ph = __builtin_amdgcn_cvt_pkrtz(h0, h1);
    const float r0 = (h0 - (float)ph[0]) * 2048.0f;
    const float r1 = (h1 - (float)ph[1]) * 2048.0f;
    const fp16x2 pl = __builtin_amdgcn_cvt_pkrtz(r0, r1);
    hph = __builtin_bit_cast(int, ph);
    hpl = __builtin_bit_cast(int, pl);
  };

  for (int t = 0; t < T_; t += 4) {
    step(pre[0], t + 0, t + 4);
    step(pre[1], t + 1, t + 5);
    step(pre[2], t + 2, t + 6);
    step(pre[3], t + 3, t + 7);
  }
}

// ---------------- Kernel C: logits = h @ Wd + bd, softmax over V=13 ----------------
__global__ __launch_bounds__(256) void dense_softmax(const float* __restrict__ hbuf,
                                                     const float* __restrict__ Wd,
                                                     const float* __restrict__ bd,
                                                     float* __restrict__ out) {
  __shared__ float4 Wds4[H_ * 4];    // Wd padded [32][16]
  __shared__ float  bds[16];
  if (threadIdx.x < 128) {
    const int j = threadIdx.x >> 2, q = threadIdx.x & 3;
    float4 v = make_float4(0.f, 0.f, 0.f, 0.f);
    const int c0 = q * 4;
    if (c0 + 0 < V_) v.x = Wd[j * V_ + c0 + 0];
    if (c0 + 1 < V_) v.y = Wd[j * V_ + c0 + 1];
    if (c0 + 2 < V_) v.z = Wd[j * V_ + c0 + 2];
    if (c0 + 3 < V_) v.w = Wd[j * V_ + c0 + 3];
    Wds4[j * 4 + q] = v;
  }
  if (threadIdx.x < 16) bds[threadIdx.x] = (threadIdx.x < V_) ? bd[threadIdx.x] : 0.f;
  __syncthreads();

  const int row = blockIdx.x * 256 + threadIdx.x;   // B*T rows, exact grid
  const float4* hr = (const float4*)(hbuf + (size_t)row * K4);  // h = first 32 floats
  float h[H_];
#pragma unroll
  for (int j = 0; j < H_ / 4; ++j) {
    float4 v = hr[j];
    h[4 * j + 0] = v.x; h[4 * j + 1] = v.y; h[4 * j + 2] = v.z; h[4 * j + 3] = v.w;
  }
  float4 acc[4];
#pragma unroll
  for (int q = 0; q < 4; ++q)
    acc[q] = make_float4(bds[4 * q], bds[4 * q + 1], bds[4 * q + 2], bds[4 * q + 3]);
#pragma unroll
  for (int j = 0; j < H_; ++j) {
    const float hj = h[j];
    fma4(acc[0], hj, Wds4[j * 4 + 0]);
    fma4(acc[1], hj, Wds4[j * 4 + 1]);
    fma4(acc[2], hj, Wds4[j * 4 + 2]);
    fma4(acc[3], hj, Wds4[j * 4 + 3]);
  }
  float lg[16];
#pragma unroll
  for (int q = 0; q < 4; ++q) {
    lg[4 * q + 0] = acc[q].x; lg[4 * q + 1] = acc[q].y;
    lg[4 * q + 2] = acc[q].z; lg[4 * q + 3] = acc[q].w;
  }
  float mx = lg[0];
#pragma unroll
  for (int v = 1; v < V_; ++v) mx = fmaxf(mx, lg[v]);
  float s = 0.f;
#pragma unroll
  for (int v = 0; v < V_; ++v) { float e = __expf(lg[v] - mx); lg[v] = e; s += e; }
  const float r = 1.f / s;
  float* orow = out + (size_t)row * V_;
#pragma unroll
  for (int v = 0; v < V_; ++v) orow[v] = lg[v] * r;
}

extern "C" void kernel_launch(void* const* d_in, const int* in_sizes, int n_in,
                              void* d_out, int out_size, void* d_ws, size_t ws_size,
                              hipStream_t stream) {
  const float* x  = (const float*)d_in[0];
  const float* W  = (const float*)d_in[1];
  const float* U  = (const float*)d_in[2];
  const float* b  = (const float*)d_in[3];
  const float* Wd = (const float*)d_in[4];
  const float* bd = (const float*)d_in[5];
  float* out  = (float*)d_out;
  float* zbuf = (float*)d_ws;                   // [B,T,128] fp32 = 134 MB

  xz_gemm<<<(B_ * T_) / 128, 256, 0, stream>>>(x, W, b, zbuf);
  lstm_scan<<<B_ / 4, 256, 0, stream>>>(zbuf, U);
  dense_softmax<<<(B_ * T_) / 256, 256, 0, stream>>>(zbuf, Wd, bd, out);
}